// Round 10
// baseline (153.375 us; speedup 1.0000x reference)
//
#include <hip/hip_runtime.h>

#define N_D 4096
#define N_OBS 131072
#define T_TOTAL (N_D + N_OBS)      // 135168
#define S_SUB 1024                 // big-step = 1.024
#define LOG2_S 10
#define N_STEPS (T_TOTAL / S_SUB)  // 132
#define DT_BIG (S_SUB * 1e-3f)
#define KSTRIDE 24                 // z[8], f[8], z''[8]
#define FLAG_MAGIC 0x0F1E2D3C

__device__ __align__(16) float g_knots[(N_STEPS + 1) * KSTRIDE];
__device__ __align__(16) float g_S[(N_STEPS + 1) * 32];

#if __has_builtin(__builtin_amdgcn_exp2f)
#define EXP2F(x) __builtin_amdgcn_exp2f(x)
#else
#define EXP2F(x) exp2f(x)
#endif

__device__ __forceinline__ float tanh_fast(float x) {
  float e = EXP2F(x * 2.8853900817779268f);
  return 1.0f - 2.0f * __builtin_amdgcn_rcpf(e + 1.0f);
}

template <int C>
__device__ __forceinline__ float dmov(float x) {
  return __int_as_float(__builtin_amdgcn_update_dpp(0, __float_as_int(x), C, 0xF, 0xF, true));
}
template <int C>
__device__ __forceinline__ int dmovi(int x) {
  return __builtin_amdgcn_update_dpp(0, x, C, 0xF, 0xF, true);
}

#define CT_X1 0xB1    // quad_perm [1,0,3,2]  = lane^1
#define CT_X2 0x4E    // quad_perm [2,3,0,1]  = lane^2
#define CT_M8 0x141   // row_half_mirror      = mirror within 8
#define CT_X8 0x128   // row_ror:8            = lane^8 within 16

#if __has_builtin(__builtin_amdgcn_permlane16_swap)
__device__ __forceinline__ void xchg16(float x, float& a, float& b) {
  auto r = __builtin_amdgcn_permlane16_swap(__float_as_int(x), __float_as_int(x), false, false);
  a = __int_as_float((int)r[0]);
  b = __int_as_float((int)r[1]);
}
__device__ __forceinline__ void xchg16i(int x, int& a, int& b) {
  auto r = __builtin_amdgcn_permlane16_swap(x, x, false, false);
  a = (int)r[0];
  b = (int)r[1];
}
#else
__device__ __forceinline__ void xchg16(float x, float& a, float& b) {
  a = x;
  b = __int_as_float(__builtin_amdgcn_ds_swizzle(__float_as_int(x), 0x401F));
}
__device__ __forceinline__ void xchg16i(int x, int& a, int& b) {
  a = x;
  b = __builtin_amdgcn_ds_swizzle(x, 0x401F);
}
#endif

__device__ __forceinline__ float sum32(float p) {
#if __has_builtin(__builtin_amdgcn_permlane32_swap)
  auto r = __builtin_amdgcn_permlane32_swap(__float_as_int(p), __float_as_int(p), false, false);
  return __int_as_float((int)r[0]) + __int_as_float((int)r[1]);
#else
  return p + __shfl_xor(p, 32, 64);
#endif
}

// single fused kernel, 129 blocks x 256 threads, 1 wave/EU (full VGPR budget):
//   block 0       = producer: serial ABM4-PECE + knot expansion + release flag
//   blocks 1..128 = consumers: prefetch decoder weights, spin, decode 1024 obs.
__global__ void __attribute__((amdgpu_waves_per_eu(1, 1))) __launch_bounds__(256)
fused(const float* __restrict__ dose_amts,
      const float* __restrict__ enc_w, const float* __restrict__ enc_b,
      const float* __restrict__ f_w1, const float* __restrict__ f_b1,
      const float* __restrict__ f_w2, const float* __restrict__ f_b2,
      const float* __restrict__ dec_w1, const float* __restrict__ dec_b1,
      const float* __restrict__ dec_w2, const float* __restrict__ dec_b2,
      int* __restrict__ flag, float* __restrict__ out) {
  if (blockIdx.x == 0) {
    // ================= producer =================
    __shared__ float sM[32 * 32];
    const int L = threadIdx.x;

    if (L < 64) {
      const int j = L & 31;
      const int half = L >> 5;

      // build M = W1 @ W2 in LDS (wave 0 builds + reads it alone)
      for (int e = L; e < 1024; e += 64) {
        const int jj = e >> 5, l = e & 31;
        float s = 0.0f;
#pragma unroll
        for (int k = 0; k < 8; ++k) s = fmaf(f_w1[jj * 8 + k], f_w2[k * 32 + l], s);
        sM[e] = s;
      }

      // runtime replay on lane ids: learn arrival order (named-scalar tree)
      int aI, bI;
      xchg16i(L, aI, bI);
      const int pI = (aI == L) ? bI : aI;
      const bool useSw = (((pI >> 4) & 1) == half);
      const int baseI = useSw ? pI : L;
      const bool selB = (baseI == bI);

      const int i0 = baseI;
      const int i1 = dmovi<CT_X1>(i0);
      const int i2 = dmovi<CT_X2>(i0), i3 = dmovi<CT_X2>(i1);
      const int i4 = dmovi<CT_M8>(i0), i5 = dmovi<CT_M8>(i1);
      const int i6 = dmovi<CT_M8>(i2), i7 = dmovi<CT_M8>(i3);
      const int i8  = dmovi<CT_X8>(i0), i9  = dmovi<CT_X8>(i1);
      const int i10 = dmovi<CT_X8>(i2), i11 = dmovi<CT_X8>(i3);
      const int i12 = dmovi<CT_X8>(i4), i13 = dmovi<CT_X8>(i5);
      const int i14 = dmovi<CT_X8>(i6), i15 = dmovi<CT_X8>(i7);

      float c0 = 0.0f;
#pragma unroll
      for (int k = 0; k < 8; ++k) c0 = fmaf(f_w1[j * 8 + k], f_b2[k], c0);
      const float cInit = (half == 0) ? c0 : 0.0f;

      // M row j, pre-permuted to butterfly arrival order — 16 NAMED registers
      const float m0  = sM[j * 32 + (i0 & 31)],  m1  = sM[j * 32 + (i1 & 31)];
      const float m2  = sM[j * 32 + (i2 & 31)],  m3  = sM[j * 32 + (i3 & 31)];
      const float m4  = sM[j * 32 + (i4 & 31)],  m5  = sM[j * 32 + (i5 & 31)];
      const float m6  = sM[j * 32 + (i6 & 31)],  m7  = sM[j * 32 + (i7 & 31)];
      const float m8  = sM[j * 32 + (i8 & 31)],  m9  = sM[j * 32 + (i9 & 31)];
      const float m10 = sM[j * 32 + (i10 & 31)], m11 = sM[j * 32 + (i11 & 31)];
      const float m12 = sM[j * 32 + (i12 & 31)], m13 = sM[j * 32 + (i13 & 31)];
      const float m14 = sM[j * 32 + (i14 & 31)], m15 = sM[j * 32 + (i15 & 31)];

      // t0 = W1 z0 + b1,  z0 = dose0 * enc_w + enc_b
      const float d0 = dose_amts[0];
      float t = f_b1[j];
#pragma unroll
      for (int k = 0; k < 8; ++k) {
        float z0k = fmaf(d0, enc_w[k], enc_b[k]);
        t = fmaf(f_w1[j * 8 + k], z0k, t);
      }

      const float H = DT_BIG, hdt = 0.5f * DT_BIG, sdt = DT_BIG / 6.0f;
      const float H24 = DT_BIG / 24.0f;
      double S = 0.0;  // prefix of h-combos, in (H/24) units

      // stage: all-register gather tree + dot (no arrays, no pointer casts)
      auto stage = [&](float hh) -> float {
        float a, b;
        xchg16(hh, a, b);
        const float g0 = selB ? b : a;
        const float g1 = dmov<CT_X1>(g0);
        const float g2 = dmov<CT_X2>(g0), g3 = dmov<CT_X2>(g1);
        const float g4 = dmov<CT_M8>(g0), g5 = dmov<CT_M8>(g1);
        const float g6 = dmov<CT_M8>(g2), g7 = dmov<CT_M8>(g3);
        const float g8  = dmov<CT_X8>(g0), g9  = dmov<CT_X8>(g1);
        const float g10 = dmov<CT_X8>(g2), g11 = dmov<CT_X8>(g3);
        const float g12 = dmov<CT_X8>(g4), g13 = dmov<CT_X8>(g5);
        const float g14 = dmov<CT_X8>(g6), g15 = dmov<CT_X8>(g7);

        float a0 = fmaf(m0, g0, cInit);
        float a1 = m1 * g1;
        float a2 = m2 * g2;
        float a3 = m3 * g3;
        a0 = fmaf(m4, g4, a0);   a1 = fmaf(m5, g5, a1);
        a2 = fmaf(m6, g6, a2);   a3 = fmaf(m7, g7, a3);
        a0 = fmaf(m8, g8, a0);   a1 = fmaf(m9, g9, a1);
        a2 = fmaf(m10, g10, a2); a3 = fmaf(m11, g11, a3);
        a0 = fmaf(m12, g12, a0); a1 = fmaf(m13, g13, a1);
        a2 = fmaf(m14, g14, a2); a3 = fmaf(m15, g15, a3);
        const float p = (a0 + a1) + (a2 + a3);
        return sum32(p);
      };

      // ---- 3 RK4 startup steps (same H), recording node values ----
      float un0, un1, un2, un3;  // u at nodes m..m-3
      float hn0, hn1, hn2;       // h at nodes m..m-2
      un1 = un2 = un3 = 0.0f; hn1 = hn2 = 0.0f;
#pragma unroll
      for (int m = 0; m < 3; ++m) {
        if (L < 32) g_S[m * 32 + j] = (float)S;
        const float h1 = tanh_fast(t);
        const float u1 = stage(h1);
        const float h2 = tanh_fast(fmaf(hdt, u1, t));
        const float u2 = stage(h2);
        const float h3 = tanh_fast(fmaf(hdt, u2, t));
        const float u3 = stage(h3);
        const float h4 = tanh_fast(fmaf(H, u3, t));
        const float u4 = stage(h4);
        un3 = un2; un2 = un1; un1 = u1;
        hn2 = hn1; hn1 = h1;
        S += (double)(4.0f * ((h1 + h4) + 2.0f * (h2 + h3)));  // RK4 in /24 units
        t = fmaf(sdt, (u1 + u4) + 2.0f * (u2 + u3), t);
      }
      // seed eval at node 3
      hn0 = tanh_fast(t);
      un0 = stage(hn0);

      // ---- ABM4 PECE main loop: nodes 3..131 ----
      for (int m = 3; m < N_STEPS; ++m) {
        if (L < 32) g_S[m * 32 + j] = (float)S;
        const float predTail = t + H24 * (-59.0f * un1 + 37.0f * un2 - 9.0f * un3);
        const float corrTail = t + H24 * (19.0f * un0 - 5.0f * un1 + un2);
        // P + E1
        const float tstar = fmaf(55.0f * H24, un0, predTail);
        const float hstar = tanh_fast(tstar);
        const float ustar = stage(hstar);
        // C + E2
        t = fmaf(9.0f * H24, ustar, corrTail);
        const float hnew = tanh_fast(t);
        const float unew = stage(hnew);
        // z-quadrature (AM4 weights, /24 units), off-path
        S += (double)(9.0f * hstar + 19.0f * hn0 - 5.0f * hn1 + hn2);
        un3 = un2; un2 = un1; un1 = un0; un0 = unew;
        hn2 = hn1; hn1 = hn0; hn0 = hnew;
      }
      if (L < 32) g_S[N_STEPS * 32 + j] = (float)S;
    }

    __syncthreads();  // g_S visible block-wide

    // ---- knot expansion: one knot per thread (133 <= 256), register-resident ----
    const int m = threadIdx.x;
    if (m <= N_STEPS) {
      const float h24 = DT_BIG / 24.0f;
      const float d0 = dose_amts[0];

      float z[8];
      {
        float acc[8];
#pragma unroll
        for (int i = 0; i < 8; ++i) acc[i] = 24.0f * (float)m * f_b2[i];
        for (int jj = 0; jj < 32; ++jj) {
          const float s = g_S[m * 32 + jj];
#pragma unroll
          for (int i = 0; i < 8; ++i) acc[i] = fmaf(f_w2[i * 32 + jj], s, acc[i]);
        }
#pragma unroll
        for (int i = 0; i < 8; ++i) z[i] = fmaf(d0, enc_w[i], enc_b[i]) + h24 * acc[i];
      }

      // pass 1: f = W2 tanh(W1 z + b1) + b2
      float f[8];
#pragma unroll
      for (int i = 0; i < 8; ++i) f[i] = f_b2[i];
      for (int jj = 0; jj < 32; ++jj) {
        float tt = f_b1[jj];
#pragma unroll
        for (int k = 0; k < 8; ++k) tt = fmaf(f_w1[jj * 8 + k], z[k], tt);
        const float h = tanh_fast(tt);
#pragma unroll
        for (int i = 0; i < 8; ++i) f[i] = fmaf(f_w2[i * 32 + jj], h, f[i]);
      }

      // pass 2: z'' = W2 [ (1-h^2) (W1 f) ]
      float zpp[8] = {0, 0, 0, 0, 0, 0, 0, 0};
      for (int jj = 0; jj < 32; ++jj) {
        float tt = f_b1[jj];
        float w = 0.0f;
#pragma unroll
        for (int k = 0; k < 8; ++k) {
          tt = fmaf(f_w1[jj * 8 + k], z[k], tt);
          w = fmaf(f_w1[jj * 8 + k], f[k], w);
        }
        const float h = tanh_fast(tt);
        const float s2 = (1.0f - h * h) * w;
#pragma unroll
        for (int i = 0; i < 8; ++i) zpp[i] = fmaf(f_w2[i * 32 + jj], s2, zpp[i]);
      }

      float* K = g_knots + (size_t)m * KSTRIDE;
#pragma unroll
      for (int i = 0; i < 8; ++i) {
        K[i] = z[i];
        K[8 + i] = f[i];
        K[16 + i] = zpp[i];
      }
    }

    __syncthreads();  // knot stores drained before release
    if (threadIdx.x == 0) {
      __hip_atomic_store(flag, FLAG_MAGIC, __ATOMIC_RELEASE, __HIP_MEMORY_SCOPE_AGENT);
    }
  } else {
    // ================= consumer =================
    // prefetch decoder weights into L1/L2 BEFORE the spin (overlaps producer)
    const float warm = dec_w1[threadIdx.x] + dec_b1[threadIdx.x & 31] +
                       dec_w2[threadIdx.x & 31];

    if (threadIdx.x == 0) {
      while (__hip_atomic_load(flag, __ATOMIC_ACQUIRE, __HIP_MEMORY_SCOPE_AGENT) != FLAG_MAGIC) {
        __builtin_amdgcn_s_sleep(32);
      }
    }
    __syncthreads();

    const float H = DT_BIG, H2 = DT_BIG * DT_BIG;

#pragma unroll
    for (int c = 0; c < 4; ++c) {
      const int i = (blockIdx.x - 1) * 1024 + c * 256 + threadIdx.x;  // 0..N_OBS-1
      const int tidx = N_D + i;
      const int m = tidx >> LOG2_S;
      const int r = tidx & (S_SUB - 1);
      const float th = (float)r * (1.0f / (float)S_SUB);

      const float t2 = th * th, t3 = t2 * th, t4 = t3 * th, t5 = t4 * th;
      const float h0 = 1.0f - 10.0f * t3 + 15.0f * t4 - 6.0f * t5;
      const float h1 = th - 6.0f * t3 + 8.0f * t4 - 3.0f * t5;
      const float h2 = 0.5f * (t2 - 3.0f * t3 + 3.0f * t4 - t5);
      const float h3 = 1.0f - h0;
      const float h4 = -4.0f * t3 + 7.0f * t4 - 3.0f * t5;
      const float h5 = 0.5f * (t3 - 2.0f * t4 + t5);

      const float4* K0 = reinterpret_cast<const float4*>(g_knots + (size_t)m * KSTRIDE);
      const float4* K1 = reinterpret_cast<const float4*>(g_knots + (size_t)(m + 1) * KSTRIDE);
      float4 za = K0[0], zb = K0[1], fa = K0[2], fb = K0[3], aa = K0[4], ab = K0[5];
      float4 zc = K1[0], zd = K1[1], fc = K1[2], fd = K1[3], ac = K1[4], ad = K1[5];

      float z0l[8] = {za.x, za.y, za.z, za.w, zb.x, zb.y, zb.z, zb.w};
      float f0l[8] = {fa.x, fa.y, fa.z, fa.w, fb.x, fb.y, fb.z, fb.w};
      float a0l[8] = {aa.x, aa.y, aa.z, aa.w, ab.x, ab.y, ab.z, ab.w};
      float z1l[8] = {zc.x, zc.y, zc.z, zc.w, zd.x, zd.y, zd.z, zd.w};
      float f1l[8] = {fc.x, fc.y, fc.z, fc.w, fd.x, fd.y, fd.z, fd.w};
      float a1l[8] = {ac.x, ac.y, ac.z, ac.w, ad.x, ad.y, ad.z, ad.w};

      float z[8];
#pragma unroll
      for (int k = 0; k < 8; ++k) {
        float p = h0 * z0l[k] + h3 * z1l[k];
        float mm = h1 * f0l[k] + h4 * f1l[k];
        float aa2 = h2 * a0l[k] + h5 * a1l[k];
        z[k] = p + H * mm + H2 * aa2;
      }

      float acc = fmaf(0.0f, warm, dec_b2[0]);  // keep the prefetch live
#pragma unroll
      for (int jj = 0; jj < 32; ++jj) {
        float t = dec_b1[jj];
#pragma unroll
        for (int k = 0; k < 8; ++k) t = fmaf(dec_w1[jj * 8 + k], z[k], t);
        t = fmaxf(t, 0.0f);
        acc = fmaf(dec_w2[jj], t, acc);
      }
      out[i] = acc;
    }
  }
}

extern "C" void kernel_launch(void* const* d_in, const int* in_sizes, int n_in,
                              void* d_out, int out_size, void* d_ws, size_t ws_size,
                              hipStream_t stream) {
  const float* dose_amts = (const float*)d_in[0];
  const float* enc_w = (const float*)d_in[3];
  const float* enc_b = (const float*)d_in[4];
  const float* f_w1 = (const float*)d_in[5];
  const float* f_b1 = (const float*)d_in[6];
  const float* f_w2 = (const float*)d_in[7];
  const float* f_b2 = (const float*)d_in[8];
  const float* dec_w1 = (const float*)d_in[9];
  const float* dec_b1 = (const float*)d_in[10];
  const float* dec_w2 = (const float*)d_in[11];
  const float* dec_b2 = (const float*)d_in[12];
  float* out = (float*)d_out;
  int* flag = (int*)d_ws;  // re-poisoned to 0xAA before every launch => != MAGIC

  fused<<<1 + N_OBS / 1024, 256, 0, stream>>>(dose_amts, enc_w, enc_b,
                                              f_w1, f_b1, f_w2, f_b2,
                                              dec_w1, dec_b1, dec_w2, dec_b2,
                                              flag, out);
}

// Round 11
// 125.515 us; speedup vs baseline: 1.2220x; 1.2220x over previous
//
#include <hip/hip_runtime.h>

#define N_D 4096
#define N_OBS 131072
#define T_TOTAL (N_D + N_OBS)      // 135168
#define S_SUB 1024                 // big-step = 1.024
#define LOG2_S 10
#define N_STEPS (T_TOTAL / S_SUB)  // 132
#define DT_BIG (S_SUB * 1e-3f)
#define KSTRIDE 24                 // z[8], f[8], z''[8]

__device__ __align__(16) float g_knots[(N_STEPS + 1) * KSTRIDE];
__device__ __align__(16) float g_S[(N_STEPS + 1) * 32];

#if __has_builtin(__builtin_amdgcn_exp2f)
#define EXP2F(x) __builtin_amdgcn_exp2f(x)
#else
#define EXP2F(x) exp2f(x)
#endif

__device__ __forceinline__ float tanh_fast(float x) {
  float e = EXP2F(x * 2.8853900817779268f);
  return 1.0f - 2.0f * __builtin_amdgcn_rcpf(e + 1.0f);
}

template <int C>
__device__ __forceinline__ float dmov(float x) {
  return __int_as_float(__builtin_amdgcn_update_dpp(0, __float_as_int(x), C, 0xF, 0xF, true));
}
template <int C>
__device__ __forceinline__ int dmovi(int x) {
  return __builtin_amdgcn_update_dpp(0, x, C, 0xF, 0xF, true);
}

#define CT_X1 0xB1    // quad_perm [1,0,3,2]  = lane^1
#define CT_X2 0x4E    // quad_perm [2,3,0,1]  = lane^2
#define CT_M8 0x141   // row_half_mirror      = mirror within 8
#define CT_X8 0x128   // row_ror:8            = lane^8 within 16

#if __has_builtin(__builtin_amdgcn_permlane16_swap)
__device__ __forceinline__ void xchg16(float x, float& a, float& b) {
  auto r = __builtin_amdgcn_permlane16_swap(__float_as_int(x), __float_as_int(x), false, false);
  a = __int_as_float((int)r[0]);
  b = __int_as_float((int)r[1]);
}
__device__ __forceinline__ void xchg16i(int x, int& a, int& b) {
  auto r = __builtin_amdgcn_permlane16_swap(x, x, false, false);
  a = (int)r[0];
  b = (int)r[1];
}
#else
__device__ __forceinline__ void xchg16(float x, float& a, float& b) {
  a = x;
  b = __int_as_float(__builtin_amdgcn_ds_swizzle(__float_as_int(x), 0x401F));
}
__device__ __forceinline__ void xchg16i(int x, int& a, int& b) {
  a = x;
  b = __builtin_amdgcn_ds_swizzle(x, 0x401F);
}
#endif

__device__ __forceinline__ float sum32(float p) {
#if __has_builtin(__builtin_amdgcn_permlane32_swap)
  auto r = __builtin_amdgcn_permlane32_swap(__float_as_int(p), __float_as_int(p), false, false);
  return __int_as_float((int)r[0]) + __int_as_float((int)r[1]);
#else
  return p + __shfl_xor(p, 32, 64);
#endif
}

// ---- kernel 1: serial ABM4-PECE integration + register-resident knot tail ----
// Standalone (no consumers / flags / atomics): tests whether the fused-kernel
// ~58us anomaly is structural to fusion.  1 block x 256 threads, 1 wave/EU.
__global__ void __attribute__((amdgpu_waves_per_eu(1, 1))) __launch_bounds__(256)
ode_abm(const float* __restrict__ dose_amts,
        const float* __restrict__ enc_w, const float* __restrict__ enc_b,
        const float* __restrict__ f_w1, const float* __restrict__ f_b1,
        const float* __restrict__ f_w2, const float* __restrict__ f_b2) {
  __shared__ float sM[32 * 32];
  const int L = threadIdx.x;

  if (L < 64) {
    const int j = L & 31;
    const int half = L >> 5;

    // build M = W1 @ W2 in LDS (wave 0 builds + reads it alone)
    for (int e = L; e < 1024; e += 64) {
      const int jj = e >> 5, l = e & 31;
      float s = 0.0f;
#pragma unroll
      for (int k = 0; k < 8; ++k) s = fmaf(f_w1[jj * 8 + k], f_w2[k * 32 + l], s);
      sM[e] = s;
    }

    // runtime replay on lane ids: learn arrival order (named-scalar tree)
    int aI, bI;
    xchg16i(L, aI, bI);
    const int pI = (aI == L) ? bI : aI;
    const bool useSw = (((pI >> 4) & 1) == half);
    const int baseI = useSw ? pI : L;
    const bool selB = (baseI == bI);

    const int i0 = baseI;
    const int i1 = dmovi<CT_X1>(i0);
    const int i2 = dmovi<CT_X2>(i0), i3 = dmovi<CT_X2>(i1);
    const int i4 = dmovi<CT_M8>(i0), i5 = dmovi<CT_M8>(i1);
    const int i6 = dmovi<CT_M8>(i2), i7 = dmovi<CT_M8>(i3);
    const int i8  = dmovi<CT_X8>(i0), i9  = dmovi<CT_X8>(i1);
    const int i10 = dmovi<CT_X8>(i2), i11 = dmovi<CT_X8>(i3);
    const int i12 = dmovi<CT_X8>(i4), i13 = dmovi<CT_X8>(i5);
    const int i14 = dmovi<CT_X8>(i6), i15 = dmovi<CT_X8>(i7);

    float c0 = 0.0f;
#pragma unroll
    for (int k = 0; k < 8; ++k) c0 = fmaf(f_w1[j * 8 + k], f_b2[k], c0);
    const float cInit = (half == 0) ? c0 : 0.0f;

    // M row j, pre-permuted to butterfly arrival order — 16 named registers
    const float m0  = sM[j * 32 + (i0 & 31)],  m1  = sM[j * 32 + (i1 & 31)];
    const float m2  = sM[j * 32 + (i2 & 31)],  m3  = sM[j * 32 + (i3 & 31)];
    const float m4  = sM[j * 32 + (i4 & 31)],  m5  = sM[j * 32 + (i5 & 31)];
    const float m6  = sM[j * 32 + (i6 & 31)],  m7  = sM[j * 32 + (i7 & 31)];
    const float m8  = sM[j * 32 + (i8 & 31)],  m9  = sM[j * 32 + (i9 & 31)];
    const float m10 = sM[j * 32 + (i10 & 31)], m11 = sM[j * 32 + (i11 & 31)];
    const float m12 = sM[j * 32 + (i12 & 31)], m13 = sM[j * 32 + (i13 & 31)];
    const float m14 = sM[j * 32 + (i14 & 31)], m15 = sM[j * 32 + (i15 & 31)];

    // t0 = W1 z0 + b1,  z0 = dose0 * enc_w + enc_b
    const float d0 = dose_amts[0];
    float t = f_b1[j];
#pragma unroll
    for (int k = 0; k < 8; ++k) {
      float z0k = fmaf(d0, enc_w[k], enc_b[k]);
      t = fmaf(f_w1[j * 8 + k], z0k, t);
    }

    const float H = DT_BIG, hdt = 0.5f * DT_BIG, sdt = DT_BIG / 6.0f;
    const float H24 = DT_BIG / 24.0f;
    float S = 0.0f;  // prefix of h-combos in (H/24) units; f32: 132-step error << bf16 floor

    auto stage = [&](float hh) -> float {
      float a, b;
      xchg16(hh, a, b);
      const float g0 = selB ? b : a;
      const float g1 = dmov<CT_X1>(g0);
      const float g2 = dmov<CT_X2>(g0), g3 = dmov<CT_X2>(g1);
      const float g4 = dmov<CT_M8>(g0), g5 = dmov<CT_M8>(g1);
      const float g6 = dmov<CT_M8>(g2), g7 = dmov<CT_M8>(g3);
      const float g8  = dmov<CT_X8>(g0), g9  = dmov<CT_X8>(g1);
      const float g10 = dmov<CT_X8>(g2), g11 = dmov<CT_X8>(g3);
      const float g12 = dmov<CT_X8>(g4), g13 = dmov<CT_X8>(g5);
      const float g14 = dmov<CT_X8>(g6), g15 = dmov<CT_X8>(g7);

      float a0 = fmaf(m0, g0, cInit);
      float a1 = m1 * g1;
      float a2 = m2 * g2;
      float a3 = m3 * g3;
      a0 = fmaf(m4, g4, a0);   a1 = fmaf(m5, g5, a1);
      a2 = fmaf(m6, g6, a2);   a3 = fmaf(m7, g7, a3);
      a0 = fmaf(m8, g8, a0);   a1 = fmaf(m9, g9, a1);
      a2 = fmaf(m10, g10, a2); a3 = fmaf(m11, g11, a3);
      a0 = fmaf(m12, g12, a0); a1 = fmaf(m13, g13, a1);
      a2 = fmaf(m14, g14, a2); a3 = fmaf(m15, g15, a3);
      const float p = (a0 + a1) + (a2 + a3);
      return sum32(p);
    };

    // ---- 3 RK4 startup steps (same H), recording node values ----
    float un0, un1, un2, un3;  // u at nodes m..m-3
    float hn0, hn1, hn2;       // h at nodes m..m-2
    un1 = un2 = un3 = 0.0f; hn1 = hn2 = 0.0f;
#pragma unroll
    for (int m = 0; m < 3; ++m) {
      g_S[m * 32 + j] = S;  // all 64 lanes; halves write identical values
      const float h1 = tanh_fast(t);
      const float u1 = stage(h1);
      const float h2 = tanh_fast(fmaf(hdt, u1, t));
      const float u2 = stage(h2);
      const float h3 = tanh_fast(fmaf(hdt, u2, t));
      const float u3 = stage(h3);
      const float h4 = tanh_fast(fmaf(H, u3, t));
      const float u4 = stage(h4);
      un3 = un2; un2 = un1; un1 = u1;
      hn2 = hn1; hn1 = h1;
      S += 4.0f * ((h1 + h4) + 2.0f * (h2 + h3));  // RK4 in /24 units
      t = fmaf(sdt, (u1 + u4) + 2.0f * (u2 + u3), t);
    }
    // seed eval at node 3
    hn0 = tanh_fast(t);
    un0 = stage(hn0);

    // ---- ABM4 PECE main loop: nodes 3..131 ----
    for (int m = 3; m < N_STEPS; ++m) {
      g_S[m * 32 + j] = S;
      const float predTail = t + H24 * (-59.0f * un1 + 37.0f * un2 - 9.0f * un3);
      const float corrTail = t + H24 * (19.0f * un0 - 5.0f * un1 + un2);
      // P + E1
      const float tstar = fmaf(55.0f * H24, un0, predTail);
      const float hstar = tanh_fast(tstar);
      const float ustar = stage(hstar);
      // C + E2
      t = fmaf(9.0f * H24, ustar, corrTail);
      const float hnew = tanh_fast(t);
      const float unew = stage(hnew);
      // z-quadrature (AM4 weights, /24 units), off critical path
      S += 9.0f * hstar + 19.0f * hn0 - 5.0f * hn1 + hn2;
      un3 = un2; un2 = un1; un1 = un0; un0 = unew;
      hn2 = hn1; hn1 = hn0; hn0 = hnew;
    }
    g_S[N_STEPS * 32 + j] = S;
  }

  __syncthreads();  // g_S visible block-wide

  // ---- knot expansion: one knot per thread (133 <= 256), register-resident ----
  const int m = threadIdx.x;
  if (m <= N_STEPS) {
    const float h24 = DT_BIG / 24.0f;
    const float d0 = dose_amts[0];

    float z[8];
    {
      float acc[8];
#pragma unroll
      for (int i = 0; i < 8; ++i) acc[i] = 24.0f * (float)m * f_b2[i];
      for (int jj = 0; jj < 32; ++jj) {
        const float s = g_S[m * 32 + jj];
#pragma unroll
        for (int i = 0; i < 8; ++i) acc[i] = fmaf(f_w2[i * 32 + jj], s, acc[i]);
      }
#pragma unroll
      for (int i = 0; i < 8; ++i) z[i] = fmaf(d0, enc_w[i], enc_b[i]) + h24 * acc[i];
    }

    // pass 1: f = W2 tanh(W1 z + b1) + b2
    float f[8];
#pragma unroll
    for (int i = 0; i < 8; ++i) f[i] = f_b2[i];
    for (int jj = 0; jj < 32; ++jj) {
      float tt = f_b1[jj];
#pragma unroll
      for (int k = 0; k < 8; ++k) tt = fmaf(f_w1[jj * 8 + k], z[k], tt);
      const float h = tanh_fast(tt);
#pragma unroll
      for (int i = 0; i < 8; ++i) f[i] = fmaf(f_w2[i * 32 + jj], h, f[i]);
    }

    // pass 2: z'' = W2 [ (1-h^2) (W1 f) ]  (h recomputed, no big arrays)
    float zpp[8] = {0, 0, 0, 0, 0, 0, 0, 0};
    for (int jj = 0; jj < 32; ++jj) {
      float tt = f_b1[jj];
      float w = 0.0f;
#pragma unroll
      for (int k = 0; k < 8; ++k) {
        tt = fmaf(f_w1[jj * 8 + k], z[k], tt);
        w = fmaf(f_w1[jj * 8 + k], f[k], w);
      }
      const float h = tanh_fast(tt);
      const float s2 = (1.0f - h * h) * w;
#pragma unroll
      for (int i = 0; i < 8; ++i) zpp[i] = fmaf(f_w2[i * 32 + jj], s2, zpp[i]);
    }

    float* K = g_knots + (size_t)m * KSTRIDE;
#pragma unroll
    for (int i = 0; i < 8; ++i) {
      K[i] = z[i];
      K[8 + i] = f[i];
      K[16 + i] = zpp[i];
    }
  }
}

// ---- kernel 2: per-observation quintic Hermite interpolation + decoder ----
__global__ void __launch_bounds__(256)
decode(const float* __restrict__ dec_w1, const float* __restrict__ dec_b1,
       const float* __restrict__ dec_w2, const float* __restrict__ dec_b2,
       float* __restrict__ out) {
  const int i = blockIdx.x * 256 + threadIdx.x;  // 0..N_OBS-1
  const int tidx = N_D + i;
  const int m = tidx >> LOG2_S;
  const int r = tidx & (S_SUB - 1);
  const float th = (float)r * (1.0f / (float)S_SUB);

  const float4* K0 = reinterpret_cast<const float4*>(g_knots + (size_t)m * KSTRIDE);
  const float4* K1 = reinterpret_cast<const float4*>(g_knots + (size_t)(m + 1) * KSTRIDE);
  float4 za = K0[0], zb = K0[1], fa = K0[2], fb = K0[3], aa = K0[4], ab = K0[5];
  float4 zc = K1[0], zd = K1[1], fc = K1[2], fd = K1[3], ac = K1[4], ad = K1[5];

  const float t2 = th * th, t3 = t2 * th, t4 = t3 * th, t5 = t4 * th;
  // quintic Hermite basis
  const float h0 = 1.0f - 10.0f * t3 + 15.0f * t4 - 6.0f * t5;
  const float h1 = th - 6.0f * t3 + 8.0f * t4 - 3.0f * t5;
  const float h2 = 0.5f * (t2 - 3.0f * t3 + 3.0f * t4 - t5);
  const float h3 = 1.0f - h0;
  const float h4 = -4.0f * t3 + 7.0f * t4 - 3.0f * t5;
  const float h5 = 0.5f * (t3 - 2.0f * t4 + t5);
  const float H = DT_BIG, H2 = DT_BIG * DT_BIG;

  float z0l[8] = {za.x, za.y, za.z, za.w, zb.x, zb.y, zb.z, zb.w};
  float f0l[8] = {fa.x, fa.y, fa.z, fa.w, fb.x, fb.y, fb.z, fb.w};
  float a0l[8] = {aa.x, aa.y, aa.z, aa.w, ab.x, ab.y, ab.z, ab.w};
  float z1l[8] = {zc.x, zc.y, zc.z, zc.w, zd.x, zd.y, zd.z, zd.w};
  float f1l[8] = {fc.x, fc.y, fc.z, fc.w, fd.x, fd.y, fd.z, fd.w};
  float a1l[8] = {ac.x, ac.y, ac.z, ac.w, ad.x, ad.y, ad.z, ad.w};

  float z[8];
#pragma unroll
  for (int k = 0; k < 8; ++k) {
    float p = h0 * z0l[k] + h3 * z1l[k];
    float mm = h1 * f0l[k] + h4 * f1l[k];
    float aa2 = h2 * a0l[k] + h5 * a1l[k];
    z[k] = p + H * mm + H2 * aa2;
  }

  float acc = dec_b2[0];
#pragma unroll
  for (int jj = 0; jj < 32; ++jj) {
    float t = dec_b1[jj];
#pragma unroll
    for (int k = 0; k < 8; ++k) t = fmaf(dec_w1[jj * 8 + k], z[k], t);
    t = fmaxf(t, 0.0f);
    acc = fmaf(dec_w2[jj], t, acc);
  }
  out[i] = acc;
}

extern "C" void kernel_launch(void* const* d_in, const int* in_sizes, int n_in,
                              void* d_out, int out_size, void* d_ws, size_t ws_size,
                              hipStream_t stream) {
  const float* dose_amts = (const float*)d_in[0];
  const float* enc_w = (const float*)d_in[3];
  const float* enc_b = (const float*)d_in[4];
  const float* f_w1 = (const float*)d_in[5];
  const float* f_b1 = (const float*)d_in[6];
  const float* f_w2 = (const float*)d_in[7];
  const float* f_b2 = (const float*)d_in[8];
  const float* dec_w1 = (const float*)d_in[9];
  const float* dec_b1 = (const float*)d_in[10];
  const float* dec_w2 = (const float*)d_in[11];
  const float* dec_b2 = (const float*)d_in[12];
  float* out = (float*)d_out;

  ode_abm<<<1, 256, 0, stream>>>(dose_amts, enc_w, enc_b, f_w1, f_b1, f_w2, f_b2);
  decode<<<N_OBS / 256, 256, 0, stream>>>(dec_w1, dec_b1, dec_w2, dec_b2, out);
}

// Round 12
// 107.320 us; speedup vs baseline: 1.4291x; 1.1695x over previous
//
#include <hip/hip_runtime.h>

#define N_D 4096
#define N_OBS 131072
#define T_TOTAL (N_D + N_OBS)      // 135168
#define S_SUB 2048                 // big-step = 2.048
#define LOG2_S 11
#define N_STEPS (T_TOTAL / S_SUB)  // 66
#define DT_BIG (S_SUB * 1e-3f)
#define KSTRIDE 24                 // z[8], f[8], z''[8]

__device__ __align__(16) float g_knots[(N_STEPS + 1) * KSTRIDE];
__device__ __align__(16) float g_S[(N_STEPS + 1) * 32];

#if __has_builtin(__builtin_amdgcn_exp2f)
#define EXP2F(x) __builtin_amdgcn_exp2f(x)
#else
#define EXP2F(x) exp2f(x)
#endif

__device__ __forceinline__ float tanh_fast(float x) {
  float e = EXP2F(x * 2.8853900817779268f);
  return 1.0f - 2.0f * __builtin_amdgcn_rcpf(e + 1.0f);
}

template <int C>
__device__ __forceinline__ float dmov(float x) {
  return __int_as_float(__builtin_amdgcn_update_dpp(0, __float_as_int(x), C, 0xF, 0xF, true));
}
template <int C>
__device__ __forceinline__ int dmovi(int x) {
  return __builtin_amdgcn_update_dpp(0, x, C, 0xF, 0xF, true);
}

#define CT_X1 0xB1    // quad_perm [1,0,3,2]  = lane^1
#define CT_X2 0x4E    // quad_perm [2,3,0,1]  = lane^2
#define CT_M8 0x141   // row_half_mirror      = mirror within 8
#define CT_X8 0x128   // row_ror:8            = lane^8 within 16

#if __has_builtin(__builtin_amdgcn_permlane16_swap)
__device__ __forceinline__ void xchg16(float x, float& a, float& b) {
  auto r = __builtin_amdgcn_permlane16_swap(__float_as_int(x), __float_as_int(x), false, false);
  a = __int_as_float((int)r[0]);
  b = __int_as_float((int)r[1]);
}
__device__ __forceinline__ void xchg16i(int x, int& a, int& b) {
  auto r = __builtin_amdgcn_permlane16_swap(x, x, false, false);
  a = (int)r[0];
  b = (int)r[1];
}
#else
__device__ __forceinline__ void xchg16(float x, float& a, float& b) {
  a = x;
  b = __int_as_float(__builtin_amdgcn_ds_swizzle(__float_as_int(x), 0x401F));
}
__device__ __forceinline__ void xchg16i(int x, int& a, int& b) {
  a = x;
  b = __builtin_amdgcn_ds_swizzle(x, 0x401F);
}
#endif

__device__ __forceinline__ float sum32(float p) {
#if __has_builtin(__builtin_amdgcn_permlane32_swap)
  auto r = __builtin_amdgcn_permlane32_swap(__float_as_int(p), __float_as_int(p), false, false);
  return __int_as_float((int)r[0]) + __int_as_float((int)r[1]);
#else
  return p + __shfl_xor(p, 32, 64);
#endif
}

// ---- kernel 1: serial ABM4-PECE integration + register-resident knot tail ----
// 1 block x 256 threads, 1 wave/EU (full VGPR budget, no spill: VGPR=132, R10/R11).
__global__ void __attribute__((amdgpu_waves_per_eu(1, 1))) __launch_bounds__(256)
ode_abm(const float* __restrict__ dose_amts,
        const float* __restrict__ enc_w, const float* __restrict__ enc_b,
        const float* __restrict__ f_w1, const float* __restrict__ f_b1,
        const float* __restrict__ f_w2, const float* __restrict__ f_b2) {
  __shared__ float sM[32 * 32];
  const int L = threadIdx.x;

  if (L < 64) {
    const int j = L & 31;
    const int half = L >> 5;

    // build M = W1 @ W2 in LDS (wave 0 builds + reads it alone)
    for (int e = L; e < 1024; e += 64) {
      const int jj = e >> 5, l = e & 31;
      float s = 0.0f;
#pragma unroll
      for (int k = 0; k < 8; ++k) s = fmaf(f_w1[jj * 8 + k], f_w2[k * 32 + l], s);
      sM[e] = s;
    }

    // runtime replay on lane ids: learn arrival order (named-scalar tree)
    int aI, bI;
    xchg16i(L, aI, bI);
    const int pI = (aI == L) ? bI : aI;
    const bool useSw = (((pI >> 4) & 1) == half);
    const int baseI = useSw ? pI : L;
    const bool selB = (baseI == bI);

    const int i0 = baseI;
    const int i1 = dmovi<CT_X1>(i0);
    const int i2 = dmovi<CT_X2>(i0), i3 = dmovi<CT_X2>(i1);
    const int i4 = dmovi<CT_M8>(i0), i5 = dmovi<CT_M8>(i1);
    const int i6 = dmovi<CT_M8>(i2), i7 = dmovi<CT_M8>(i3);
    const int i8  = dmovi<CT_X8>(i0), i9  = dmovi<CT_X8>(i1);
    const int i10 = dmovi<CT_X8>(i2), i11 = dmovi<CT_X8>(i3);
    const int i12 = dmovi<CT_X8>(i4), i13 = dmovi<CT_X8>(i5);
    const int i14 = dmovi<CT_X8>(i6), i15 = dmovi<CT_X8>(i7);

    float c0 = 0.0f;
#pragma unroll
    for (int k = 0; k < 8; ++k) c0 = fmaf(f_w1[j * 8 + k], f_b2[k], c0);
    const float cInit = (half == 0) ? c0 : 0.0f;

    // M row j, pre-permuted to butterfly arrival order — 16 named registers
    const float m0  = sM[j * 32 + (i0 & 31)],  m1  = sM[j * 32 + (i1 & 31)];
    const float m2  = sM[j * 32 + (i2 & 31)],  m3  = sM[j * 32 + (i3 & 31)];
    const float m4  = sM[j * 32 + (i4 & 31)],  m5  = sM[j * 32 + (i5 & 31)];
    const float m6  = sM[j * 32 + (i6 & 31)],  m7  = sM[j * 32 + (i7 & 31)];
    const float m8  = sM[j * 32 + (i8 & 31)],  m9  = sM[j * 32 + (i9 & 31)];
    const float m10 = sM[j * 32 + (i10 & 31)], m11 = sM[j * 32 + (i11 & 31)];
    const float m12 = sM[j * 32 + (i12 & 31)], m13 = sM[j * 32 + (i13 & 31)];
    const float m14 = sM[j * 32 + (i14 & 31)], m15 = sM[j * 32 + (i15 & 31)];

    // t0 = W1 z0 + b1,  z0 = dose0 * enc_w + enc_b
    const float d0 = dose_amts[0];
    float t = f_b1[j];
#pragma unroll
    for (int k = 0; k < 8; ++k) {
      float z0k = fmaf(d0, enc_w[k], enc_b[k]);
      t = fmaf(f_w1[j * 8 + k], z0k, t);
    }

    const float H = DT_BIG, hdt = 0.5f * DT_BIG, sdt = DT_BIG / 6.0f;
    const float H24 = DT_BIG / 24.0f;
    float S = 0.0f;  // prefix of h-combos in (H/24) units

    auto stage = [&](float hh) -> float {
      float a, b;
      xchg16(hh, a, b);
      const float g0 = selB ? b : a;
      const float g1 = dmov<CT_X1>(g0);
      const float g2 = dmov<CT_X2>(g0), g3 = dmov<CT_X2>(g1);
      const float g4 = dmov<CT_M8>(g0), g5 = dmov<CT_M8>(g1);
      const float g6 = dmov<CT_M8>(g2), g7 = dmov<CT_M8>(g3);
      const float g8  = dmov<CT_X8>(g0), g9  = dmov<CT_X8>(g1);
      const float g10 = dmov<CT_X8>(g2), g11 = dmov<CT_X8>(g3);
      const float g12 = dmov<CT_X8>(g4), g13 = dmov<CT_X8>(g5);
      const float g14 = dmov<CT_X8>(g6), g15 = dmov<CT_X8>(g7);

      float a0 = fmaf(m0, g0, cInit);
      float a1 = m1 * g1;
      float a2 = m2 * g2;
      float a3 = m3 * g3;
      a0 = fmaf(m4, g4, a0);   a1 = fmaf(m5, g5, a1);
      a2 = fmaf(m6, g6, a2);   a3 = fmaf(m7, g7, a3);
      a0 = fmaf(m8, g8, a0);   a1 = fmaf(m9, g9, a1);
      a2 = fmaf(m10, g10, a2); a3 = fmaf(m11, g11, a3);
      a0 = fmaf(m12, g12, a0); a1 = fmaf(m13, g13, a1);
      a2 = fmaf(m14, g14, a2); a3 = fmaf(m15, g15, a3);
      const float p = (a0 + a1) + (a2 + a3);
      return sum32(p);
    };

    // ---- 3 RK4 startup steps (same H), recording node values ----
    float un0, un1, un2, un3;  // u at nodes m..m-3
    float hn0, hn1, hn2;       // h at nodes m..m-2
    un1 = un2 = un3 = 0.0f; hn1 = hn2 = 0.0f;
#pragma unroll
    for (int m = 0; m < 3; ++m) {
      g_S[m * 32 + j] = S;  // all 64 lanes; halves write identical values
      const float h1 = tanh_fast(t);
      const float u1 = stage(h1);
      const float h2 = tanh_fast(fmaf(hdt, u1, t));
      const float u2 = stage(h2);
      const float h3 = tanh_fast(fmaf(hdt, u2, t));
      const float u3 = stage(h3);
      const float h4 = tanh_fast(fmaf(H, u3, t));
      const float u4 = stage(h4);
      un3 = un2; un2 = un1; un1 = u1;
      hn2 = hn1; hn1 = h1;
      S += 4.0f * ((h1 + h4) + 2.0f * (h2 + h3));  // RK4 in /24 units
      t = fmaf(sdt, (u1 + u4) + 2.0f * (u2 + u3), t);
    }
    // seed eval at node 3
    hn0 = tanh_fast(t);
    un0 = stage(hn0);

    // ---- ABM4 PECE main loop: nodes 3..N_STEPS-1 ----
    for (int m = 3; m < N_STEPS; ++m) {
      g_S[m * 32 + j] = S;
      const float predTail = t + H24 * (-59.0f * un1 + 37.0f * un2 - 9.0f * un3);
      const float corrTail = t + H24 * (19.0f * un0 - 5.0f * un1 + un2);
      // P + E1
      const float tstar = fmaf(55.0f * H24, un0, predTail);
      const float hstar = tanh_fast(tstar);
      const float ustar = stage(hstar);
      // C + E2
      t = fmaf(9.0f * H24, ustar, corrTail);
      const float hnew = tanh_fast(t);
      const float unew = stage(hnew);
      // z-quadrature (AM4 weights, /24 units), off critical path
      S += 9.0f * hstar + 19.0f * hn0 - 5.0f * hn1 + hn2;
      un3 = un2; un2 = un1; un1 = un0; un0 = unew;
      hn2 = hn1; hn1 = hn0; hn0 = hnew;
    }
    g_S[N_STEPS * 32 + j] = S;
  }

  __syncthreads();  // g_S visible block-wide

  // ---- knot expansion: one knot per thread (67 <= 256), register-resident ----
  const int m = threadIdx.x;
  if (m <= N_STEPS) {
    const float h24 = DT_BIG / 24.0f;
    const float d0 = dose_amts[0];

    float z[8];
    {
      float acc[8];
#pragma unroll
      for (int i = 0; i < 8; ++i) acc[i] = 24.0f * (float)m * f_b2[i];
      for (int jj = 0; jj < 32; ++jj) {
        const float s = g_S[m * 32 + jj];
#pragma unroll
        for (int i = 0; i < 8; ++i) acc[i] = fmaf(f_w2[i * 32 + jj], s, acc[i]);
      }
#pragma unroll
      for (int i = 0; i < 8; ++i) z[i] = fmaf(d0, enc_w[i], enc_b[i]) + h24 * acc[i];
    }

    // pass 1: f = W2 tanh(W1 z + b1) + b2
    float f[8];
#pragma unroll
    for (int i = 0; i < 8; ++i) f[i] = f_b2[i];
    for (int jj = 0; jj < 32; ++jj) {
      float tt = f_b1[jj];
#pragma unroll
      for (int k = 0; k < 8; ++k) tt = fmaf(f_w1[jj * 8 + k], z[k], tt);
      const float h = tanh_fast(tt);
#pragma unroll
      for (int i = 0; i < 8; ++i) f[i] = fmaf(f_w2[i * 32 + jj], h, f[i]);
    }

    // pass 2: z'' = W2 [ (1-h^2) (W1 f) ]  (h recomputed, no big arrays)
    float zpp[8] = {0, 0, 0, 0, 0, 0, 0, 0};
    for (int jj = 0; jj < 32; ++jj) {
      float tt = f_b1[jj];
      float w = 0.0f;
#pragma unroll
      for (int k = 0; k < 8; ++k) {
        tt = fmaf(f_w1[jj * 8 + k], z[k], tt);
        w = fmaf(f_w1[jj * 8 + k], f[k], w);
      }
      const float h = tanh_fast(tt);
      const float s2 = (1.0f - h * h) * w;
#pragma unroll
      for (int i = 0; i < 8; ++i) zpp[i] = fmaf(f_w2[i * 32 + jj], s2, zpp[i]);
    }

    float* K = g_knots + (size_t)m * KSTRIDE;
#pragma unroll
    for (int i = 0; i < 8; ++i) {
      K[i] = z[i];
      K[8 + i] = f[i];
      K[16 + i] = zpp[i];
    }
  }
}

// ---- kernel 2: per-observation quintic Hermite interpolation + decoder ----
__global__ void __launch_bounds__(256)
decode(const float* __restrict__ dec_w1, const float* __restrict__ dec_b1,
       const float* __restrict__ dec_w2, const float* __restrict__ dec_b2,
       float* __restrict__ out) {
  const int i = blockIdx.x * 256 + threadIdx.x;  // 0..N_OBS-1
  const int tidx = N_D + i;
  const int m = tidx >> LOG2_S;
  const int r = tidx & (S_SUB - 1);
  const float th = (float)r * (1.0f / (float)S_SUB);

  const float4* K0 = reinterpret_cast<const float4*>(g_knots + (size_t)m * KSTRIDE);
  const float4* K1 = reinterpret_cast<const float4*>(g_knots + (size_t)(m + 1) * KSTRIDE);
  float4 za = K0[0], zb = K0[1], fa = K0[2], fb = K0[3], aa = K0[4], ab = K0[5];
  float4 zc = K1[0], zd = K1[1], fc = K1[2], fd = K1[3], ac = K1[4], ad = K1[5];

  const float t2 = th * th, t3 = t2 * th, t4 = t3 * th, t5 = t4 * th;
  // quintic Hermite basis
  const float h0 = 1.0f - 10.0f * t3 + 15.0f * t4 - 6.0f * t5;
  const float h1 = th - 6.0f * t3 + 8.0f * t4 - 3.0f * t5;
  const float h2 = 0.5f * (t2 - 3.0f * t3 + 3.0f * t4 - t5);
  const float h3 = 1.0f - h0;
  const float h4 = -4.0f * t3 + 7.0f * t4 - 3.0f * t5;
  const float h5 = 0.5f * (t3 - 2.0f * t4 + t5);
  const float H = DT_BIG, H2 = DT_BIG * DT_BIG;

  float z0l[8] = {za.x, za.y, za.z, za.w, zb.x, zb.y, zb.z, zb.w};
  float f0l[8] = {fa.x, fa.y, fa.z, fa.w, fb.x, fb.y, fb.z, fb.w};
  float a0l[8] = {aa.x, aa.y, aa.z, aa.w, ab.x, ab.y, ab.z, ab.w};
  float z1l[8] = {zc.x, zc.y, zc.z, zc.w, zd.x, zd.y, zd.z, zd.w};
  float f1l[8] = {fc.x, fc.y, fc.z, fc.w, fd.x, fd.y, fd.z, fd.w};
  float a1l[8] = {ac.x, ac.y, ac.z, ac.w, ad.x, ad.y, ad.z, ad.w};

  float z[8];
#pragma unroll
  for (int k = 0; k < 8; ++k) {
    float p = h0 * z0l[k] + h3 * z1l[k];
    float mm = h1 * f0l[k] + h4 * f1l[k];
    float aa2 = h2 * a0l[k] + h5 * a1l[k];
    z[k] = p + H * mm + H2 * aa2;
  }

  float acc = dec_b2[0];
#pragma unroll
  for (int jj = 0; jj < 32; ++jj) {
    float t = dec_b1[jj];
#pragma unroll
    for (int k = 0; k < 8; ++k) t = fmaf(dec_w1[jj * 8 + k], z[k], t);
    t = fmaxf(t, 0.0f);
    acc = fmaf(dec_w2[jj], t, acc);
  }
  out[i] = acc;
}

extern "C" void kernel_launch(void* const* d_in, const int* in_sizes, int n_in,
                              void* d_out, int out_size, void* d_ws, size_t ws_size,
                              hipStream_t stream) {
  const float* dose_amts = (const float*)d_in[0];
  const float* enc_w = (const float*)d_in[3];
  const float* enc_b = (const float*)d_in[4];
  const float* f_w1 = (const float*)d_in[5];
  const float* f_b1 = (const float*)d_in[6];
  const float* f_w2 = (const float*)d_in[7];
  const float* f_b2 = (const float*)d_in[8];
  const float* dec_w1 = (const float*)d_in[9];
  const float* dec_b1 = (const float*)d_in[10];
  const float* dec_w2 = (const float*)d_in[11];
  const float* dec_b2 = (const float*)d_in[12];
  float* out = (float*)d_out;

  ode_abm<<<1, 256, 0, stream>>>(dose_amts, enc_w, enc_b, f_w1, f_b1, f_w2, f_b2);
  decode<<<N_OBS / 256, 256, 0, stream>>>(dec_w1, dec_b1, dec_w2, dec_b2, out);
}

// Round 13
// 101.931 us; speedup vs baseline: 1.5047x; 1.0529x over previous
//
#include <hip/hip_runtime.h>

#define N_D 4096
#define N_OBS 131072
#define T_TOTAL (N_D + N_OBS)      // 135168
#define S_SUB 4096                 // big-step = 4.096
#define LOG2_S 12
#define N_STEPS (T_TOTAL / S_SUB)  // 33
#define DT_BIG (S_SUB * 1e-3f)
#define KSTRIDE 24                 // z[8], f[8], z''[8]

__device__ __align__(16) float g_knots[(N_STEPS + 1) * KSTRIDE];
__device__ __align__(16) float g_S[(N_STEPS + 1) * 32];

#if __has_builtin(__builtin_amdgcn_exp2f)
#define EXP2F(x) __builtin_amdgcn_exp2f(x)
#else
#define EXP2F(x) exp2f(x)
#endif

__device__ __forceinline__ float tanh_fast(float x) {
  float e = EXP2F(x * 2.8853900817779268f);
  return 1.0f - 2.0f * __builtin_amdgcn_rcpf(e + 1.0f);
}

template <int C>
__device__ __forceinline__ float dmov(float x) {
  return __int_as_float(__builtin_amdgcn_update_dpp(0, __float_as_int(x), C, 0xF, 0xF, true));
}
template <int C>
__device__ __forceinline__ int dmovi(int x) {
  return __builtin_amdgcn_update_dpp(0, x, C, 0xF, 0xF, true);
}

#define CT_X1 0xB1    // quad_perm [1,0,3,2]  = lane^1
#define CT_X2 0x4E    // quad_perm [2,3,0,1]  = lane^2
#define CT_M8 0x141   // row_half_mirror      = mirror within 8
#define CT_X8 0x128   // row_ror:8            = lane^8 within 16

#if __has_builtin(__builtin_amdgcn_permlane16_swap)
__device__ __forceinline__ void xchg16(float x, float& a, float& b) {
  auto r = __builtin_amdgcn_permlane16_swap(__float_as_int(x), __float_as_int(x), false, false);
  a = __int_as_float((int)r[0]);
  b = __int_as_float((int)r[1]);
}
__device__ __forceinline__ void xchg16i(int x, int& a, int& b) {
  auto r = __builtin_amdgcn_permlane16_swap(x, x, false, false);
  a = (int)r[0];
  b = (int)r[1];
}
#else
__device__ __forceinline__ void xchg16(float x, float& a, float& b) {
  a = x;
  b = __int_as_float(__builtin_amdgcn_ds_swizzle(__float_as_int(x), 0x401F));
}
__device__ __forceinline__ void xchg16i(int x, int& a, int& b) {
  a = x;
  b = __builtin_amdgcn_ds_swizzle(x, 0x401F);
}
#endif

__device__ __forceinline__ float sum32(float p) {
#if __has_builtin(__builtin_amdgcn_permlane32_swap)
  auto r = __builtin_amdgcn_permlane32_swap(__float_as_int(p), __float_as_int(p), false, false);
  return __int_as_float((int)r[0]) + __int_as_float((int)r[1]);
#else
  return p + __shfl_xor(p, 32, 64);
#endif
}

// ---- kernel 1: serial integration + register-resident knot tail ----
// Startup: 3 nodes x (2 RK4 substeps @ H/2 = known-accurate 2.048).
// Main: ABM4 PECE at H = 4.096.  1 block x 256 threads, 1 wave/EU.
__global__ void __attribute__((amdgpu_waves_per_eu(1, 1))) __launch_bounds__(256)
ode_abm(const float* __restrict__ dose_amts,
        const float* __restrict__ enc_w, const float* __restrict__ enc_b,
        const float* __restrict__ f_w1, const float* __restrict__ f_b1,
        const float* __restrict__ f_w2, const float* __restrict__ f_b2) {
  __shared__ float sM[32 * 32];
  const int L = threadIdx.x;

  if (L < 64) {
    const int j = L & 31;
    const int half = L >> 5;

    // build M = W1 @ W2 in LDS (wave 0 builds + reads it alone)
    for (int e = L; e < 1024; e += 64) {
      const int jj = e >> 5, l = e & 31;
      float s = 0.0f;
#pragma unroll
      for (int k = 0; k < 8; ++k) s = fmaf(f_w1[jj * 8 + k], f_w2[k * 32 + l], s);
      sM[e] = s;
    }

    // runtime replay on lane ids: learn arrival order (named-scalar tree)
    int aI, bI;
    xchg16i(L, aI, bI);
    const int pI = (aI == L) ? bI : aI;
    const bool useSw = (((pI >> 4) & 1) == half);
    const int baseI = useSw ? pI : L;
    const bool selB = (baseI == bI);

    const int i0 = baseI;
    const int i1 = dmovi<CT_X1>(i0);
    const int i2 = dmovi<CT_X2>(i0), i3 = dmovi<CT_X2>(i1);
    const int i4 = dmovi<CT_M8>(i0), i5 = dmovi<CT_M8>(i1);
    const int i6 = dmovi<CT_M8>(i2), i7 = dmovi<CT_M8>(i3);
    const int i8  = dmovi<CT_X8>(i0), i9  = dmovi<CT_X8>(i1);
    const int i10 = dmovi<CT_X8>(i2), i11 = dmovi<CT_X8>(i3);
    const int i12 = dmovi<CT_X8>(i4), i13 = dmovi<CT_X8>(i5);
    const int i14 = dmovi<CT_X8>(i6), i15 = dmovi<CT_X8>(i7);

    float c0 = 0.0f;
#pragma unroll
    for (int k = 0; k < 8; ++k) c0 = fmaf(f_w1[j * 8 + k], f_b2[k], c0);
    const float cInit = (half == 0) ? c0 : 0.0f;

    // M row j, pre-permuted to butterfly arrival order — 16 named registers
    const float m0  = sM[j * 32 + (i0 & 31)],  m1  = sM[j * 32 + (i1 & 31)];
    const float m2  = sM[j * 32 + (i2 & 31)],  m3  = sM[j * 32 + (i3 & 31)];
    const float m4  = sM[j * 32 + (i4 & 31)],  m5  = sM[j * 32 + (i5 & 31)];
    const float m6  = sM[j * 32 + (i6 & 31)],  m7  = sM[j * 32 + (i7 & 31)];
    const float m8  = sM[j * 32 + (i8 & 31)],  m9  = sM[j * 32 + (i9 & 31)];
    const float m10 = sM[j * 32 + (i10 & 31)], m11 = sM[j * 32 + (i11 & 31)];
    const float m12 = sM[j * 32 + (i12 & 31)], m13 = sM[j * 32 + (i13 & 31)];
    const float m14 = sM[j * 32 + (i14 & 31)], m15 = sM[j * 32 + (i15 & 31)];

    // t0 = W1 z0 + b1,  z0 = dose0 * enc_w + enc_b
    const float d0 = dose_amts[0];
    float t = f_b1[j];
#pragma unroll
    for (int k = 0; k < 8; ++k) {
      float z0k = fmaf(d0, enc_w[k], enc_b[k]);
      t = fmaf(f_w1[j * 8 + k], z0k, t);
    }

    const float H24 = DT_BIG / 24.0f;
    const float hh = 0.5f * DT_BIG;   // substep size H/2
    const float hq = 0.25f * DT_BIG;  // substep half  H/4
    const float s12 = DT_BIG / 12.0f; // substep /6 = H/12
    float S = 0.0f;  // prefix of h-combos in (H/24) units

    auto stage = [&](float hhv) -> float {
      float a, b;
      xchg16(hhv, a, b);
      const float g0 = selB ? b : a;
      const float g1 = dmov<CT_X1>(g0);
      const float g2 = dmov<CT_X2>(g0), g3 = dmov<CT_X2>(g1);
      const float g4 = dmov<CT_M8>(g0), g5 = dmov<CT_M8>(g1);
      const float g6 = dmov<CT_M8>(g2), g7 = dmov<CT_M8>(g3);
      const float g8  = dmov<CT_X8>(g0), g9  = dmov<CT_X8>(g1);
      const float g10 = dmov<CT_X8>(g2), g11 = dmov<CT_X8>(g3);
      const float g12 = dmov<CT_X8>(g4), g13 = dmov<CT_X8>(g5);
      const float g14 = dmov<CT_X8>(g6), g15 = dmov<CT_X8>(g7);

      float a0 = fmaf(m0, g0, cInit);
      float a1 = m1 * g1;
      float a2 = m2 * g2;
      float a3 = m3 * g3;
      a0 = fmaf(m4, g4, a0);   a1 = fmaf(m5, g5, a1);
      a2 = fmaf(m6, g6, a2);   a3 = fmaf(m7, g7, a3);
      a0 = fmaf(m8, g8, a0);   a1 = fmaf(m9, g9, a1);
      a2 = fmaf(m10, g10, a2); a3 = fmaf(m11, g11, a3);
      a0 = fmaf(m12, g12, a0); a1 = fmaf(m13, g13, a1);
      a2 = fmaf(m14, g14, a2); a3 = fmaf(m15, g15, a3);
      const float p = (a0 + a1) + (a2 + a3);
      return sum32(p);
    };

    // ---- 3 startup nodes, each = 2 RK4 substeps at H/2 (known-accurate) ----
    float un0, un1, un2, un3;  // u at nodes m..m-3 (H spacing)
    float hn0, hn1, hn2;       // h at nodes m..m-2
    un1 = un2 = un3 = 0.0f; hn1 = hn2 = 0.0f;
#pragma unroll
    for (int m = 0; m < 3; ++m) {
      g_S[m * 32 + j] = S;  // all 64 lanes; halves write identical values
      // substep A (records node-m values)
      {
        const float h1 = tanh_fast(t);
        const float u1 = stage(h1);
        un3 = un2; un2 = un1; un1 = u1;
        hn2 = hn1; hn1 = h1;
        const float h2 = tanh_fast(fmaf(hq, u1, t));
        const float u2 = stage(h2);
        const float h3 = tanh_fast(fmaf(hq, u2, t));
        const float u3 = stage(h3);
        const float h4 = tanh_fast(fmaf(hh, u3, t));
        const float u4 = stage(h4);
        S += 2.0f * ((h1 + h4) + 2.0f * (h2 + h3));  // Simpson at H/2, /24 units
        t = fmaf(s12, (u1 + u4) + 2.0f * (u2 + u3), t);
      }
      // substep B
      {
        const float h1 = tanh_fast(t);
        const float u1 = stage(h1);
        const float h2 = tanh_fast(fmaf(hq, u1, t));
        const float u2 = stage(h2);
        const float h3 = tanh_fast(fmaf(hq, u2, t));
        const float u3 = stage(h3);
        const float h4 = tanh_fast(fmaf(hh, u3, t));
        const float u4 = stage(h4);
        S += 2.0f * ((h1 + h4) + 2.0f * (h2 + h3));
        t = fmaf(s12, (u1 + u4) + 2.0f * (u2 + u3), t);
      }
    }
    // seed eval at node 3
    hn0 = tanh_fast(t);
    un0 = stage(hn0);

    // ---- ABM4 PECE main loop at full H: nodes 3..N_STEPS-1 ----
    for (int m = 3; m < N_STEPS; ++m) {
      g_S[m * 32 + j] = S;
      const float predTail = t + H24 * (-59.0f * un1 + 37.0f * un2 - 9.0f * un3);
      const float corrTail = t + H24 * (19.0f * un0 - 5.0f * un1 + un2);
      // P + E1
      const float tstar = fmaf(55.0f * H24, un0, predTail);
      const float hstar = tanh_fast(tstar);
      const float ustar = stage(hstar);
      // C + E2
      t = fmaf(9.0f * H24, ustar, corrTail);
      const float hnew = tanh_fast(t);
      const float unew = stage(hnew);
      // z-quadrature (AM4 weights, /24 units), off critical path
      S += 9.0f * hstar + 19.0f * hn0 - 5.0f * hn1 + hn2;
      un3 = un2; un2 = un1; un1 = un0; un0 = unew;
      hn2 = hn1; hn1 = hn0; hn0 = hnew;
    }
    g_S[N_STEPS * 32 + j] = S;
  }

  __syncthreads();  // g_S visible block-wide

  // ---- knot expansion: one knot per thread (34 <= 256), register-resident ----
  const int m = threadIdx.x;
  if (m <= N_STEPS) {
    const float h24 = DT_BIG / 24.0f;
    const float d0 = dose_amts[0];

    float z[8];
    {
      float acc[8];
#pragma unroll
      for (int i = 0; i < 8; ++i) acc[i] = 24.0f * (float)m * f_b2[i];
      for (int jj = 0; jj < 32; ++jj) {
        const float s = g_S[m * 32 + jj];
#pragma unroll
        for (int i = 0; i < 8; ++i) acc[i] = fmaf(f_w2[i * 32 + jj], s, acc[i]);
      }
#pragma unroll
      for (int i = 0; i < 8; ++i) z[i] = fmaf(d0, enc_w[i], enc_b[i]) + h24 * acc[i];
    }

    // pass 1: f = W2 tanh(W1 z + b1) + b2
    float f[8];
#pragma unroll
    for (int i = 0; i < 8; ++i) f[i] = f_b2[i];
    for (int jj = 0; jj < 32; ++jj) {
      float tt = f_b1[jj];
#pragma unroll
      for (int k = 0; k < 8; ++k) tt = fmaf(f_w1[jj * 8 + k], z[k], tt);
      const float h = tanh_fast(tt);
#pragma unroll
      for (int i = 0; i < 8; ++i) f[i] = fmaf(f_w2[i * 32 + jj], h, f[i]);
    }

    // pass 2: z'' = W2 [ (1-h^2) (W1 f) ]  (h recomputed, no big arrays)
    float zpp[8] = {0, 0, 0, 0, 0, 0, 0, 0};
    for (int jj = 0; jj < 32; ++jj) {
      float tt = f_b1[jj];
      float w = 0.0f;
#pragma unroll
      for (int k = 0; k < 8; ++k) {
        tt = fmaf(f_w1[jj * 8 + k], z[k], tt);
        w = fmaf(f_w1[jj * 8 + k], f[k], w);
      }
      const float h = tanh_fast(tt);
      const float s2 = (1.0f - h * h) * w;
#pragma unroll
      for (int i = 0; i < 8; ++i) zpp[i] = fmaf(f_w2[i * 32 + jj], s2, zpp[i]);
    }

    float* K = g_knots + (size_t)m * KSTRIDE;
#pragma unroll
    for (int i = 0; i < 8; ++i) {
      K[i] = z[i];
      K[8 + i] = f[i];
      K[16 + i] = zpp[i];
    }
  }
}

// ---- kernel 2: per-observation quintic Hermite interpolation + decoder ----
__global__ void __launch_bounds__(256)
decode(const float* __restrict__ dec_w1, const float* __restrict__ dec_b1,
       const float* __restrict__ dec_w2, const float* __restrict__ dec_b2,
       float* __restrict__ out) {
  const int i = blockIdx.x * 256 + threadIdx.x;  // 0..N_OBS-1
  const int tidx = N_D + i;
  const int m = tidx >> LOG2_S;
  const int r = tidx & (S_SUB - 1);
  const float th = (float)r * (1.0f / (float)S_SUB);

  const float4* K0 = reinterpret_cast<const float4*>(g_knots + (size_t)m * KSTRIDE);
  const float4* K1 = reinterpret_cast<const float4*>(g_knots + (size_t)(m + 1) * KSTRIDE);
  float4 za = K0[0], zb = K0[1], fa = K0[2], fb = K0[3], aa = K0[4], ab = K0[5];
  float4 zc = K1[0], zd = K1[1], fc = K1[2], fd = K1[3], ac = K1[4], ad = K1[5];

  const float t2 = th * th, t3 = t2 * th, t4 = t3 * th, t5 = t4 * th;
  // quintic Hermite basis
  const float h0 = 1.0f - 10.0f * t3 + 15.0f * t4 - 6.0f * t5;
  const float h1 = th - 6.0f * t3 + 8.0f * t4 - 3.0f * t5;
  const float h2 = 0.5f * (t2 - 3.0f * t3 + 3.0f * t4 - t5);
  const float h3 = 1.0f - h0;
  const float h4 = -4.0f * t3 + 7.0f * t4 - 3.0f * t5;
  const float h5 = 0.5f * (t3 - 2.0f * t4 + t5);
  const float H = DT_BIG, H2 = DT_BIG * DT_BIG;

  float z0l[8] = {za.x, za.y, za.z, za.w, zb.x, zb.y, zb.z, zb.w};
  float f0l[8] = {fa.x, fa.y, fa.z, fa.w, fb.x, fb.y, fb.z, fb.w};
  float a0l[8] = {aa.x, aa.y, aa.z, aa.w, ab.x, ab.y, ab.z, ab.w};
  float z1l[8] = {zc.x, zc.y, zc.z, zc.w, zd.x, zd.y, zd.z, zd.w};
  float f1l[8] = {fc.x, fc.y, fc.z, fc.w, fd.x, fd.y, fd.z, fd.w};
  float a1l[8] = {ac.x, ac.y, ac.z, ac.w, ad.x, ad.y, ad.z, ad.w};

  float z[8];
#pragma unroll
  for (int k = 0; k < 8; ++k) {
    float p = h0 * z0l[k] + h3 * z1l[k];
    float mm = h1 * f0l[k] + h4 * f1l[k];
    float aa2 = h2 * a0l[k] + h5 * a1l[k];
    z[k] = p + H * mm + H2 * aa2;
  }

  float acc = dec_b2[0];
#pragma unroll
  for (int jj = 0; jj < 32; ++jj) {
    float t = dec_b1[jj];
#pragma unroll
    for (int k = 0; k < 8; ++k) t = fmaf(dec_w1[jj * 8 + k], z[k], t);
    t = fmaxf(t, 0.0f);
    acc = fmaf(dec_w2[jj], t, acc);
  }
  out[i] = acc;
}

extern "C" void kernel_launch(void* const* d_in, const int* in_sizes, int n_in,
                              void* d_out, int out_size, void* d_ws, size_t ws_size,
                              hipStream_t stream) {
  const float* dose_amts = (const float*)d_in[0];
  const float* enc_w = (const float*)d_in[3];
  const float* enc_b = (const float*)d_in[4];
  const float* f_w1 = (const float*)d_in[5];
  const float* f_b1 = (const float*)d_in[6];
  const float* f_w2 = (const float*)d_in[7];
  const float* f_b2 = (const float*)d_in[8];
  const float* dec_w1 = (const float*)d_in[9];
  const float* dec_b1 = (const float*)d_in[10];
  const float* dec_w2 = (const float*)d_in[11];
  const float* dec_b2 = (const float*)d_in[12];
  float* out = (float*)d_out;

  ode_abm<<<1, 256, 0, stream>>>(dose_amts, enc_w, enc_b, f_w1, f_b1, f_w2, f_b2);
  decode<<<N_OBS / 256, 256, 0, stream>>>(dec_w1, dec_b1, dec_w2, dec_b2, out);
}